// Round 2
// baseline (417.009 us; speedup 1.0000x reference)
//
#include <hip/hip_runtime.h>
#include <hip/hip_bf16.h>

#define M_DIM 8192   // 4 * 2048 rows of x
#define N_DIM 8192   // out_features
#define K_DIM 2048   // in_features

typedef float f32x4 __attribute__((ext_vector_type(4)));
typedef short s16x8 __attribute__((ext_vector_type(8)));   // 8 bf16 (4 VGPRs)
typedef unsigned short u16;
typedef u16 u16x8 __attribute__((ext_vector_type(8)));
typedef unsigned int u32;
typedef u32 u32x4 __attribute__((ext_vector_type(4)));
typedef int i32x4 __attribute__((ext_vector_type(4)));

// ---------- helpers ----------

__device__ __forceinline__ u16 cvt_bf16_rne(float f) {
    u32 u = __builtin_bit_cast(u32, f);
    u += 0x7fffu + ((u >> 16) & 1u);   // round-to-nearest-even; inputs are finite
    return (u16)(u >> 16);
}

__device__ __forceinline__ void gload16(const u16* g, u16* l) {
    // 16B global -> LDS direct (global_load_lds_dwordx4). LDS dest is
    // wave-uniform base + lane*16 — our layout satisfies this by construction.
    __builtin_amdgcn_global_load_lds(
        (const __attribute__((address_space(1))) u32*)g,
        (__attribute__((address_space(3))) u32*)l, 16, 0, 0);
}

// ---------- prepass: fp32 x -> bf16 ----------

__global__ void __launch_bounds__(256) cvt_x_k(const float* __restrict__ x,
                                               u16* __restrict__ xb, int n8) {
    const int stride = gridDim.x * blockDim.x;
    for (int i = blockIdx.x * blockDim.x + threadIdx.x; i < n8; i += stride) {
        const f32x4* p = (const f32x4*)x + (size_t)i * 2;
        f32x4 a = p[0], b = p[1];
        u16x8 o;
        o[0] = cvt_bf16_rne(a[0]); o[1] = cvt_bf16_rne(a[1]);
        o[2] = cvt_bf16_rne(a[2]); o[3] = cvt_bf16_rne(a[3]);
        o[4] = cvt_bf16_rne(b[0]); o[5] = cvt_bf16_rne(b[1]);
        o[6] = cvt_bf16_rne(b[2]); o[7] = cvt_bf16_rne(b[3]);
        *((u16x8*)xb + i) = o;
    }
}

// ---------- prepass: int32 (harness materializes int8 as int32) -> bf16 ----------
// Values in [-128,127]: exact in bf16. Scale applied in fp32 epilogue (exact).

__global__ void __launch_bounds__(256) cvt_w_k(const int* __restrict__ w,
                                               u16* __restrict__ wb, int n8) {
    const int stride = gridDim.x * blockDim.x;
    for (int i = blockIdx.x * blockDim.x + threadIdx.x; i < n8; i += stride) {
        const i32x4* p = (const i32x4*)w + (size_t)i * 2;
        i32x4 a = p[0], b = p[1];
        u16x8 o;
        o[0] = cvt_bf16_rne((float)a[0]); o[1] = cvt_bf16_rne((float)a[1]);
        o[2] = cvt_bf16_rne((float)a[2]); o[3] = cvt_bf16_rne((float)a[3]);
        o[4] = cvt_bf16_rne((float)b[0]); o[5] = cvt_bf16_rne((float)b[1]);
        o[6] = cvt_bf16_rne((float)b[2]); o[7] = cvt_bf16_rne((float)b[3]);
        *((u16x8*)wb + i) = o;
    }
}

// ---------- main GEMM: C[m][n] = (A_bf16 @ B_bf16^T)*scale[n] + bias[n] ----------
// m97 structure: 128x128 tile, BK=32, 4 waves (2x2), 4x4 16x16x32 frags/wave,
// global_load_lds width-16 staging, 2-barrier K loop.

__global__ void __launch_bounds__(256) gemm_k(const u16* __restrict__ A,
                                              const u16* __restrict__ B,
                                              const float* __restrict__ scale,
                                              const float* __restrict__ bias,
                                              float* __restrict__ C) {
    __shared__ __align__(16) u16 As[128 * 32];
    __shared__ __align__(16) u16 Bs[128 * 32];

    // XCD-bijective swizzle: 4096 blocks, 4096 % 8 == 0
    const int bid = blockIdx.x;
    const int swz = (bid & 7) * 512 + (bid >> 3);
    const int bm = swz >> 6;
    const int bn = swz & 63;
    const int rowBase = bm * 128;
    const int colBase = bn * 128;

    const int t = threadIdx.x;
    const int l = t & 63;
    const int w = t >> 6;
    const int wm = w >> 1;   // wave tile row (0..1), each wave owns 64x64
    const int wn = w & 1;    // wave tile col

    // staging: thread t stages elements t*8..t*8+7 of each [64][32] half-tile
    const int srow = t >> 2;            // 0..63
    const int skk  = (t & 3) * 8;       // 0,8,16,24

    const u16* a0 = A + (size_t)(rowBase + srow) * K_DIM + skk;
    const u16* a1 = A + (size_t)(rowBase + 64 + srow) * K_DIM + skk;
    const u16* b0 = B + (size_t)(colBase + srow) * K_DIM + skk;
    const u16* b1 = B + (size_t)(colBase + 64 + srow) * K_DIM + skk;

    u16* lA0 = &As[t * 8];
    u16* lA1 = &As[2048 + t * 8];
    u16* lB0 = &Bs[t * 8];
    u16* lB1 = &Bs[2048 + t * 8];

    f32x4 acc[4][4] = {};

    const int koff = (l >> 4) * 8;   // k sub-offset of this lane's fragment
    const int frow = l & 15;         // row/col within 16x16 fragment

    for (int k0 = 0; k0 < K_DIM; k0 += 32) {
        gload16(a0 + k0, lA0);
        gload16(a1 + k0, lA1);
        gload16(b0 + k0, lB0);
        gload16(b1 + k0, lB1);
        __syncthreads();   // compiler emits vmcnt(0) drain before s_barrier

        s16x8 af[4], bf[4];
#pragma unroll
        for (int mi = 0; mi < 4; ++mi)
            af[mi] = *(const s16x8*)&As[(wm * 64 + mi * 16 + frow) * 32 + koff];
#pragma unroll
        for (int ni = 0; ni < 4; ++ni)
            bf[ni] = *(const s16x8*)&Bs[(wn * 64 + ni * 16 + frow) * 32 + koff];

#pragma unroll
        for (int mi = 0; mi < 4; ++mi)
#pragma unroll
            for (int ni = 0; ni < 4; ++ni)
                acc[mi][ni] = __builtin_amdgcn_mfma_f32_16x16x32_bf16(
                    af[mi], bf[ni], acc[mi][ni], 0, 0, 0);

        __syncthreads();   // protect LDS before next stage
    }

    // epilogue: C/D layout col=lane&15, row=(lane>>4)*4+reg (m89/m91)
    const int crow = rowBase + wm * 64 + (l >> 4) * 4;
    const int ccol = colBase + wn * 64 + (l & 15);
#pragma unroll
    for (int ni = 0; ni < 4; ++ni) {
        const int col = ccol + ni * 16;
        const float s = scale[col];
        const float bz = bias[col];
#pragma unroll
        for (int mi = 0; mi < 4; ++mi) {
            const int row = crow + mi * 16;
            f32x4 v = acc[mi][ni];
#pragma unroll
            for (int r = 0; r < 4; ++r)
                C[(size_t)(row + r) * N_DIM + col] = v[r] * s + bz;
        }
    }
}

// ---------- correctness fallback if workspace too small (should not trigger) ----------

__global__ void __launch_bounds__(256) naive_k(const float* __restrict__ x,
                                               const int* __restrict__ w,
                                               const float* __restrict__ scale,
                                               const float* __restrict__ bias,
                                               float* __restrict__ out) {
    __shared__ float xs[K_DIM];
    const int m = blockIdx.x >> 5;                       // 32 col-chunks of 256
    const int n = ((blockIdx.x & 31) << 8) + threadIdx.x;
    for (int i = threadIdx.x; i < K_DIM; i += 256) xs[i] = x[(size_t)m * K_DIM + i];
    __syncthreads();
    const int* wr = w + (size_t)n * K_DIM;
    float acc = 0.f;
    for (int k = 0; k < K_DIM; k += 4) {
        i32x4 v = *(const i32x4*)(wr + k);
        acc += xs[k]     * (float)v[0];
        acc += xs[k + 1] * (float)v[1];
        acc += xs[k + 2] * (float)v[2];
        acc += xs[k + 3] * (float)v[3];
    }
    out[(size_t)m * N_DIM + n] = acc * scale[n] + bias[n];
}

// ---------- launch ----------

extern "C" void kernel_launch(void* const* d_in, const int* in_sizes, int n_in,
                              void* d_out, int out_size, void* d_ws, size_t ws_size,
                              hipStream_t stream) {
    const float* x     = (const float*)d_in[0];
    const int*   w8    = (const int*)d_in[1];     // int8 values stored as int32
    const float* scale = (const float*)d_in[2];
    const float* bias  = (const float*)d_in[3];
    float*       out   = (float*)d_out;

    const size_t need = ((size_t)M_DIM * K_DIM + (size_t)N_DIM * K_DIM) * sizeof(u16); // 64 MB
    if (ws_size >= need) {
        u16* xb = (u16*)d_ws;
        u16* wb = xb + (size_t)M_DIM * K_DIM;
        cvt_x_k<<<2048, 256, 0, stream>>>(x, xb, M_DIM * K_DIM / 8);
        cvt_w_k<<<2048, 256, 0, stream>>>(w8, wb, N_DIM * K_DIM / 8);
        gemm_k<<<4096, 256, 0, stream>>>(xb, wb, scale, bias, out);
    } else {
        naive_k<<<(M_DIM * (N_DIM / 256)), 256, 0, stream>>>(x, w8, scale, bias, out);
    }
}

// Round 3
// 339.878 us; speedup vs baseline: 1.2269x; 1.2269x over previous
//
#include <hip/hip_runtime.h>
#include <hip/hip_bf16.h>

#define M_DIM 8192   // 4 * 2048 rows of x
#define N_DIM 8192   // out_features
#define K_DIM 2048   // in_features

// GEMM geometry: 256x256 tile, BK=32, 512 threads = 8 waves (2 M x 4 N),
// per-wave 128x64 output = acc[8][4] of 16x16 frags. 4 LDS slots (deep pipe).
#define BK 32
#define SLOT_BYTES 32768     // A 16KB + B 16KB per K-tile
#define NT (K_DIM / BK)      // 64 K-tiles

typedef float f32x4 __attribute__((ext_vector_type(4)));
typedef short s16x8 __attribute__((ext_vector_type(8)));
typedef unsigned short u16;
typedef u16 u16x8 __attribute__((ext_vector_type(8)));
typedef unsigned int u32;
typedef u32 u32x4 __attribute__((ext_vector_type(4)));
typedef int i32x4 __attribute__((ext_vector_type(4)));

// ---------- helpers ----------

__device__ __forceinline__ u16 cvt_bf16_rne(float f) {
    u32 u = __builtin_bit_cast(u32, f);
    u += 0x7fffu + ((u >> 16) & 1u);
    return (u16)(u >> 16);
}

__device__ __forceinline__ void gload16(const u16* g, u16* l) {
    // global_load_lds_dwordx4: LDS dest is wave-uniform base + lane*16 (linear).
    __builtin_amdgcn_global_load_lds(
        (const __attribute__((address_space(1))) u32*)g,
        (__attribute__((address_space(3))) u32*)l, 16, 0, 0);
}

// ---------- prepass: fp32 x -> bf16 ----------

__global__ void __launch_bounds__(256) cvt_x_k(const float* __restrict__ x,
                                               u16* __restrict__ xb, int n8) {
    const int stride = gridDim.x * blockDim.x;
    for (int i = blockIdx.x * blockDim.x + threadIdx.x; i < n8; i += stride) {
        const f32x4* p = (const f32x4*)x + (size_t)i * 2;
        f32x4 a = p[0], b = p[1];
        u16x8 o;
        o[0] = cvt_bf16_rne(a[0]); o[1] = cvt_bf16_rne(a[1]);
        o[2] = cvt_bf16_rne(a[2]); o[3] = cvt_bf16_rne(a[3]);
        o[4] = cvt_bf16_rne(b[0]); o[5] = cvt_bf16_rne(b[1]);
        o[6] = cvt_bf16_rne(b[2]); o[7] = cvt_bf16_rne(b[3]);
        *((u16x8*)xb + i) = o;
    }
}

// ---------- prepass: int32 (harness materializes int8 as int32) -> bf16 ----------

__global__ void __launch_bounds__(256) cvt_w_k(const int* __restrict__ w,
                                               u16* __restrict__ wb, int n8) {
    const int stride = gridDim.x * blockDim.x;
    for (int i = blockIdx.x * blockDim.x + threadIdx.x; i < n8; i += stride) {
        const i32x4* p = (const i32x4*)w + (size_t)i * 2;
        i32x4 a = p[0], b = p[1];
        u16x8 o;
        o[0] = cvt_bf16_rne((float)a[0]); o[1] = cvt_bf16_rne((float)a[1]);
        o[2] = cvt_bf16_rne((float)a[2]); o[3] = cvt_bf16_rne((float)a[3]);
        o[4] = cvt_bf16_rne((float)b[0]); o[5] = cvt_bf16_rne((float)b[1]);
        o[6] = cvt_bf16_rne((float)b[2]); o[7] = cvt_bf16_rne((float)b[3]);
        *((u16x8*)wb + i) = o;
    }
}

// ---------- main GEMM ----------
// LDS slot layout (bytes within slot): A[256 rows][64B] at 0, B[256 rows][64B] at 16384.
// Physical 16B-chunk p of row r holds global k-slot (p ^ ((r>>1)&3)) — 2-way-max
// bank aliasing on ds_read_b128 (free, m136). Swizzle applied on the GLOBAL
// source address (linear LDS dest for global_load_lds) and on the read address.

__global__ void __launch_bounds__(512, 2)
gemm_k(const u16* __restrict__ A, const u16* __restrict__ B,
       const float* __restrict__ scale, const float* __restrict__ bias,
       float* __restrict__ C) {
    extern __shared__ __align__(16) char ldsb[];

    // XCD-bijective swizzle: 1024 blocks, 1024 % 8 == 0
    const int bid = blockIdx.x;
    const int swz = (bid & 7) * 128 + (bid >> 3);
    const int rowBase = (swz >> 5) * 256;
    const int colBase = (swz & 31) * 256;

    const int t = threadIdx.x;       // 0..511
    const int l = t & 63;
    const int w = t >> 6;            // 0..7
    const int wm = w >> 2;           // 0..1  (128-row half)
    const int wn = w & 3;            // 0..3  (64-col quarter)

    // --- staging addressing (4 x global_load_lds per thread per K-tile) ---
    const int sr = t >> 2;                    // row 0..127 within half
    const int sp = t & 3;                     // phys 16B chunk
    const int sk = ((sp ^ ((sr >> 1) & 3)) * 8);  // swizzled global k-offset (elems)
    const u16* gA0 = A + (size_t)(rowBase + sr) * K_DIM + sk;
    const u16* gA1 = A + (size_t)(rowBase + 128 + sr) * K_DIM + sk;
    const u16* gB0 = B + (size_t)(colBase + sr) * K_DIM + sk;
    const u16* gB1 = B + (size_t)(colBase + 128 + sr) * K_DIM + sk;

#define STAGE(tk) do { \
        char* _b = ldsb + ((tk) & 3) * SLOT_BYTES; \
        const int _k = (tk) * BK; \
        gload16(gA0 + _k, (u16*)(_b + t * 16)); \
        gload16(gA1 + _k, (u16*)(_b + 8192 + t * 16)); \
        gload16(gB0 + _k, (u16*)(_b + 16384 + t * 16)); \
        gload16(gB1 + _k, (u16*)(_b + 24576 + t * 16)); \
    } while (0)

    // --- fragment read offsets (bytes within slot), swizzled ---
    const int fr = l & 15;
    const int s4 = l >> 4;           // k-slot 0..3 (8 elems each)
    int aoff[8], boff[4];
#pragma unroll
    for (int mi = 0; mi < 8; ++mi) {
        const int ra = wm * 128 + mi * 16 + fr;
        aoff[mi] = ra * 64 + ((s4 ^ ((ra >> 1) & 3)) * 16);
    }
#pragma unroll
    for (int ni = 0; ni < 4; ++ni) {
        const int rb = wn * 64 + ni * 16 + fr;
        boff[ni] = 16384 + rb * 64 + ((s4 ^ ((rb >> 1) & 3)) * 16);
    }

    f32x4 acc[8][4] = {};

#define BODY(tk) do { \
        __builtin_amdgcn_s_barrier(); \
        __builtin_amdgcn_sched_barrier(0); \
        const char* _sb = ldsb + ((tk) & 3) * SLOT_BYTES; \
        s16x8 af[8], bf[4]; \
        _Pragma("unroll") \
        for (int mi = 0; mi < 8; ++mi) af[mi] = *(const s16x8*)(_sb + aoff[mi]); \
        _Pragma("unroll") \
        for (int ni = 0; ni < 4; ++ni) bf[ni] = *(const s16x8*)(_sb + boff[ni]); \
        __builtin_amdgcn_s_setprio(1); \
        _Pragma("unroll") \
        for (int mi = 0; mi < 8; ++mi) \
            _Pragma("unroll") \
            for (int ni = 0; ni < 4; ++ni) \
                acc[mi][ni] = __builtin_amdgcn_mfma_f32_16x16x32_bf16( \
                    af[mi], bf[ni], acc[mi][ni], 0, 0, 0); \
        __builtin_amdgcn_s_setprio(0); \
        __builtin_amdgcn_s_barrier(); \
        __builtin_amdgcn_sched_barrier(0); \
    } while (0)

    // prologue: 3 K-tiles in flight
    STAGE(0); STAGE(1); STAGE(2);

    // main loop: stage tile tk+3 (slot last read at iter tk-1, separated by the
    // trailing barrier), keep 12 loads in flight; vmcnt(12) => tile tk landed.
#pragma unroll 1
    for (int tk = 0; tk < NT - 3; ++tk) {
        STAGE(tk + 3);
        asm volatile("s_waitcnt vmcnt(12)" ::: "memory");
        BODY(tk);
    }
    asm volatile("s_waitcnt vmcnt(8)" ::: "memory");
    BODY(NT - 3);
    asm volatile("s_waitcnt vmcnt(4)" ::: "memory");
    BODY(NT - 2);
    asm volatile("s_waitcnt vmcnt(0)" ::: "memory");
    BODY(NT - 1);

#undef STAGE
#undef BODY

    // epilogue: C/D layout col=lane&15, row=(lane>>4)*4+reg (verified round 2)
    const int crow0 = rowBase + wm * 128 + (l >> 4) * 4;
    const int ccol0 = colBase + wn * 64 + (l & 15);
#pragma unroll
    for (int ni = 0; ni < 4; ++ni) {
        const int col = ccol0 + ni * 16;
        const float s = scale[col];
        const float bz = bias[col];
#pragma unroll
        for (int mi = 0; mi < 8; ++mi) {
            const int row = crow0 + mi * 16;
            f32x4 v = acc[mi][ni];
#pragma unroll
            for (int r = 0; r < 4; ++r)
                C[(size_t)(row + r) * N_DIM + col] = v[r] * s + bz;
        }
    }
}

// ---------- correctness fallback if workspace too small (should not trigger) ----------

__global__ void __launch_bounds__(256) naive_k(const float* __restrict__ x,
                                               const int* __restrict__ w,
                                               const float* __restrict__ scale,
                                               const float* __restrict__ bias,
                                               float* __restrict__ out) {
    __shared__ float xs[K_DIM];
    const int m = blockIdx.x >> 5;
    const int n = ((blockIdx.x & 31) << 8) + threadIdx.x;
    for (int i = threadIdx.x; i < K_DIM; i += 256) xs[i] = x[(size_t)m * K_DIM + i];
    __syncthreads();
    const int* wr = w + (size_t)n * K_DIM;
    float acc = 0.f;
    for (int k = 0; k < K_DIM; k += 4) {
        i32x4 v = *(const i32x4*)(wr + k);
        acc += xs[k]     * (float)v[0];
        acc += xs[k + 1] * (float)v[1];
        acc += xs[k + 2] * (float)v[2];
        acc += xs[k + 3] * (float)v[3];
    }
    out[(size_t)m * N_DIM + n] = acc * scale[n] + bias[n];
}

// ---------- launch ----------

extern "C" void kernel_launch(void* const* d_in, const int* in_sizes, int n_in,
                              void* d_out, int out_size, void* d_ws, size_t ws_size,
                              hipStream_t stream) {
    const float* x     = (const float*)d_in[0];
    const int*   w8    = (const int*)d_in[1];
    const float* scale = (const float*)d_in[2];
    const float* bias  = (const float*)d_in[3];
    float*       out   = (float*)d_out;

    const size_t need = ((size_t)M_DIM * K_DIM + (size_t)N_DIM * K_DIM) * sizeof(u16);
    if (ws_size >= need) {
        u16* xb = (u16*)d_ws;
        u16* wb = xb + (size_t)M_DIM * K_DIM;
        hipFuncSetAttribute((const void*)gemm_k,
                            hipFuncAttributeMaxDynamicSharedMemorySize, 131072);
        cvt_x_k<<<2048, 256, 0, stream>>>(x, xb, M_DIM * K_DIM / 8);
        cvt_w_k<<<2048, 256, 0, stream>>>(w8, wb, N_DIM * K_DIM / 8);
        gemm_k<<<dim3((M_DIM / 256) * (N_DIM / 256)), 512, 131072, stream>>>(
            xb, wb, scale, bias, out);
    } else {
        naive_k<<<(M_DIM * (N_DIM / 256)), 256, 0, stream>>>(x, w8, scale, bias, out);
    }
}